// Round 7
// baseline (210.424 us; speedup 1.0000x reference)
//
#include <hip/hip_runtime.h>
#include <math.h>

#define BB 32
#define DD 256
#define KK 2048
#define HW 1024
#define CHW (DD*HW)
#define NN (BB*HW)         // 32768 rows
#define BETA 0.25f
#define NCAND 8
#define RROWS 32
#define BIAS 0.125f

typedef __attribute__((ext_vector_type(8))) short short8v;   // 8 bf16 (4 VGPR)
typedef __attribute__((ext_vector_type(4))) float f32x4;

typedef const __attribute__((address_space(1))) void gv_t;
typedef __attribute__((address_space(3))) void lv_t;

__device__ __forceinline__ void gl_lds16(const void* g, void* l) {
    // LDS dest = wave-uniform base (+ lane*16 by HW); global src = per-lane addr
    __builtin_amdgcn_global_load_lds((gv_t*)g, (lv_t*)l, 16, 0, 0);
}

__device__ __forceinline__ unsigned bfr(float f) {           // fp32 -> bf16 RNE
    unsigned u = __float_as_uint(f);
    return (u + 0x7FFFu + ((u >> 16) & 1u)) >> 16;
}
__device__ __forceinline__ unsigned bfpack(float lo, float hi) {
    return bfr(lo) | (bfr(hi) << 16);
}

#define BARRIER() do { asm volatile("" ::: "memory"); \
                       __builtin_amdgcn_s_barrier();  \
                       asm volatile("" ::: "memory"); } while (0)

// ---- prep: blocks 0..255 convert E->bf16 tiled; blocks 256..263 compute C ----
// EbfT unit u = t*2048 + c*256 + kc*64 + code64   (t = 64-code tile)
__global__ __launch_bounds__(256) void k_prep(const float* __restrict__ E,
                                              uint4* __restrict__ EbfT,
                                              float* __restrict__ Cref,
                                              float* __restrict__ Ckey) {
    int bid = blockIdx.x;
    if (bid < 256) {
        int u = bid * 256 + threadIdx.x;                 // 0..65535
        int code = u & 63, kc = (u >> 6) & 3, c = (u >> 8) & 7, t = u >> 11;
        int k = t * 64 + code;
        const float* s = E + ((size_t)k * DD + c * 32 + kc * 8);
        float4 f0 = *reinterpret_cast<const float4*>(s);
        float4 f1 = *reinterpret_cast<const float4*>(s + 4);
        uint4 o;
        o.x = bfpack(f0.x, f0.y); o.y = bfpack(f0.z, f0.w);
        o.z = bfpack(f1.x, f1.y); o.w = bfpack(f1.z, f1.w);
        EbfT[u] = o;
    } else {
        int k = (bid - 256) * 256 + threadIdx.x;
        const float* e = E + (size_t)k * DD;
        float res;
        {
#pragma clang fp contract(off)
            float r0[8], r1[8];
            #pragma unroll
            for (int j = 0; j < 8; ++j) { float t = e[j];       r0[j] = t * t; }
            #pragma unroll
            for (int j = 0; j < 8; ++j) { float t = e[128 + j]; r1[j] = t * t; }
            for (int i = 8; i < 128; i += 8) {
                #pragma unroll
                for (int j = 0; j < 8; ++j) { float t = e[i + j];       r0[j] += t * t; }
                #pragma unroll
                for (int j = 0; j < 8; ++j) { float t = e[128 + i + j]; r1[j] += t * t; }
            }
            float lo = ((r0[0]+r0[1])+(r0[2]+r0[3]))+((r0[4]+r0[5])+(r0[6]+r0[7]));
            float hi = ((r1[0]+r1[1])+(r1[2]+r1[3]))+((r1[4]+r1[5])+(r1[6]+r1[7]));
            res = lo + hi;
        }
        Cref[k] = res;
        Ckey[k] = res + BIAS;
    }
}

// ---- MFMA screen v3: 512 thr, 128 rows/block, A in regs (fp32->bf16 inline),
//      E LDS double-buffer with counted vmcnt (no per-tile drain) ----
__global__ __launch_bounds__(512, 2) void k_screen(
        const float* __restrict__ X, const uint4* __restrict__ EbfT,
        const float* __restrict__ Ckey, int* __restrict__ ck)
{
    __shared__ __align__(1024) char lds[90112]; // 64KB Edbuf | 16KB scr | 8KB ckey

    const int tid = threadIdx.x;
    const int w = tid >> 6;              // 0..7
    const int wr = w >> 1, wc = w & 1;   // 4 row-groups x 2 code-groups
    const int lane = tid & 63;
    const int lid = lane & 15, kc = lane >> 4;
    const int nb = blockIdx.x * 128;
    const int b = nb >> 10;              // 128 | 1024 -> single b per block
    const int hw0 = nb & 1023;

    // Ckey -> LDS (reads in-loop must be LGKM, not VMEM, to keep vmcnt exact)
    float* ckl = (float*)(lds + 81920);
    #pragma unroll
    for (int i = 0; i < 4; ++i) ckl[tid + i * 512] = Ckey[tid + i * 512];

    // ---- A-fragments: rows nb+wr*32+rt*16+lid, d = c*32+kc*8+j  (64 VGPR) ----
    short8v a[8][2];
    {
        const float* xb = X + (size_t)b * CHW + (hw0 + wr * 32 + lid);
        #pragma unroll
        for (int c = 0; c < 8; ++c)
            #pragma unroll
            for (int rt = 0; rt < 2; ++rt) {
                const float* pp = xb + rt * 16 + (size_t)(c * 32 + kc * 8) * HW;
                float f[8];
                #pragma unroll
                for (int j = 0; j < 8; ++j) f[j] = pp[(size_t)j * HW];
                uint4 v;
                v.x = bfpack(f[0], f[1]); v.y = bfpack(f[2], f[3]);
                v.z = bfpack(f[4], f[5]); v.w = bfpack(f[6], f[7]);
                a[c][rt] = *reinterpret_cast<short8v*>(&v);
            }
    }

    // ---- staging: 8 waves x 4 insts x 1KB = 32KB tile ----
    auto stage = [&](int t, int p) {
        const uint4* src = EbfT + ((size_t)t * 2048 + w * 256 + lane);
        char* dst = lds + p * 32768 + (w * 256) * 16;
        #pragma unroll
        for (int i = 0; i < 4; ++i)
            gl_lds16(src + i * 64, dst + i * 1024);
    };

    stage(0, 0);
    stage(1, 1);
    asm volatile("s_waitcnt lgkmcnt(0)" ::: "memory");   // ckl writes visible
    asm volatile("s_waitcnt vmcnt(4)" ::: "memory");     // tile0 arrived
    BARRIER();

    unsigned t1[2][2][4], t2[2][2][4], t3[2][2][4];      // per (rt,ct,g) top-3
    #pragma unroll
    for (int i = 0; i < 2; ++i)
        #pragma unroll
        for (int j = 0; j < 2; ++j)
            #pragma unroll
            for (int g = 0; g < 4; ++g) {
                t1[i][j][g] = 0xFFFFFFFFu; t2[i][j][g] = 0xFFFFFFFFu;
                t3[i][j][g] = 0xFFFFFFFFu;
            }

    int p = 0;
    for (int t = 0; t < 32; ++t) {
        const short8v* Ev = reinterpret_cast<const short8v*>(lds + p * 32768);
        float ckv[2];
        #pragma unroll
        for (int ct = 0; ct < 2; ++ct)
            ckv[ct] = ckl[t * 64 + wc * 32 + ct * 16 + lid];

        f32x4 acc[2][2];
        #pragma unroll
        for (int i = 0; i < 2; ++i)
            #pragma unroll
            for (int j = 0; j < 2; ++j) acc[i][j] = (f32x4){0.f, 0.f, 0.f, 0.f};

        #pragma unroll
        for (int c = 0; c < 8; ++c) {
            short8v b0 = Ev[c * 256 + kc * 64 + wc * 32 + lid];
            short8v b1 = Ev[c * 256 + kc * 64 + wc * 32 + 16 + lid];
            acc[0][0] = __builtin_amdgcn_mfma_f32_16x16x32_bf16(a[c][0], b0, acc[0][0], 0, 0, 0);
            acc[1][0] = __builtin_amdgcn_mfma_f32_16x16x32_bf16(a[c][1], b0, acc[1][0], 0, 0, 0);
            acc[0][1] = __builtin_amdgcn_mfma_f32_16x16x32_bf16(a[c][0], b1, acc[0][1], 0, 0, 0);
            acc[1][1] = __builtin_amdgcn_mfma_f32_16x16x32_bf16(a[c][1], b1, acc[1][1], 0, 0, 0);
        }

        // key = (score bits & ~31) | t ; top-3 insert per (row, code-slot)
        #pragma unroll
        for (int rt = 0; rt < 2; ++rt)
            #pragma unroll
            for (int ct = 0; ct < 2; ++ct)
                #pragma unroll
                for (int g = 0; g < 4; ++g) {
                    float s = fmaf(-2.0f, acc[rt][ct][g], ckv[ct]);
                    unsigned key = (__float_as_uint(s) & 0xFFFFFFE0u) | (unsigned)t;
                    unsigned o1 = t1[rt][ct][g];
                    unsigned lo = key < o1 ? key : o1;
                    unsigned hi = key < o1 ? o1 : key;
                    t1[rt][ct][g] = lo;
                    unsigned o2 = t2[rt][ct][g];
                    unsigned m2 = hi < o2 ? hi : o2;
                    unsigned h2 = hi < o2 ? o2 : hi;
                    t2[rt][ct][g] = m2;
                    unsigned o3 = t3[rt][ct][g];
                    t3[rt][ct][g] = h2 < o3 ? h2 : o3;
                }

        BARRIER();                                   // all done reading buf p
        if (t < 30) {
            stage(t + 2, p);                         // refill buf p
            asm volatile("s_waitcnt vmcnt(4)" ::: "memory");  // t+1 arrived
        } else {
            asm volatile("s_waitcnt vmcnt(0)" ::: "memory");  // final drain
        }
        BARRIER();                                   // whole t+1 tile valid
        p ^= 1;
    }

    // ---- merge: 64 slots/row x 3 keys -> top-8, two 64-row passes ----
    uint4* mb = reinterpret_cast<uint4*>(lds);            // [64 rows][64 slots]
    uint2* scr = reinterpret_cast<uint2*>(lds + 65536);   // [64][4][8]
    for (int pass = 0; pass < 2; ++pass) {
        BARRIER();
        if ((wr >> 1) == pass) {
            #pragma unroll
            for (int rt = 0; rt < 2; ++rt)
                #pragma unroll
                for (int g = 0; g < 4; ++g) {
                    int row = (wr & 1) * 32 + rt * 16 + kc * 4 + g;
                    #pragma unroll
                    for (int ct = 0; ct < 2; ++ct) {
                        uint4 v;
                        v.x = t1[rt][ct][g]; v.y = t2[rt][ct][g];
                        v.z = t3[rt][ct][g]; v.w = 0xFFFFFFFFu;
                        mb[row * 64 + wc * 32 + ct * 16 + lid] = v;
                    }
                }
        }
        BARRIER();
        if (tid < 256) {
            int row = tid >> 2, q = tid & 3;
            uint4 kv[16]; int sl[16];
            #pragma unroll
            for (int s = 0; s < 16; ++s) {
                int slot = q * 16 + ((s + tid) & 15);     // bank-spread rotation
                kv[s] = mb[row * 64 + slot];
                sl[s] = slot;
            }
            unsigned prev = 0; int prevj = -1;
            for (int i = 0; i < 8; ++i) {
                unsigned cur = 0xFFFFFFFFu; int curj = 0x7FFFFFFF;
                #pragma unroll
                for (int s = 0; s < 16; ++s) {
                    int j0 = sl[s] * 4;
                    { unsigned k2=kv[s].x; int j=j0;   if ((k2>prev||(k2==prev&&j>prevj)) && (k2<cur||(k2==cur&&j<curj))) {cur=k2;curj=j;} }
                    { unsigned k2=kv[s].y; int j=j0+1; if ((k2>prev||(k2==prev&&j>prevj)) && (k2<cur||(k2==cur&&j<curj))) {cur=k2;curj=j;} }
                    { unsigned k2=kv[s].z; int j=j0+2; if ((k2>prev||(k2==prev&&j>prevj)) && (k2<cur||(k2==cur&&j<curj))) {cur=k2;curj=j;} }
                }
                uint2 pr; pr.x = cur; pr.y = (unsigned)curj;
                scr[(row * 4 + q) * 8 + i] = pr;
                prev = cur; prevj = curj;
            }
        }
        BARRIER();
        if (tid < 64) {
            unsigned prev = 0; int prevj = -1;
            for (int i = 0; i < 8; ++i) {
                unsigned cur = 0xFFFFFFFFu; int curj = 0x7FFFFFFF;
                for (int m = 0; m < 32; ++m) {
                    int mm = (m + tid) & 31;
                    uint2 pr = scr[tid * 32 + mm];
                    unsigned k2 = pr.x; int j = (int)pr.y;
                    if ((k2>prev||(k2==prev&&j>prevj)) && (k2<cur||(k2==cur&&j<curj))) {cur=k2;curj=j;}
                }
                prev = cur; prevj = curj;
                int code = (int)(cur & 31u) * 64 + (curj >> 2);   // k = t*64 + slot
                ck[(size_t)(nb + pass * 64 + tid) * NCAND + i] = code;
            }
        }
    }
}

// ---- refine: bitwise numpy-fp32 rescore of 8 candidates (1 thread/(row,cand)) ----
__global__ __launch_bounds__(256) void k_refine(const float* __restrict__ X,
                                                const float* __restrict__ E,
                                                const float* __restrict__ Cref,
                                                const int* __restrict__ ck,
                                                float* __restrict__ idx_out_f,
                                                int* __restrict__ ind) {
    __shared__ float Xl[RROWS][DD + 4];
    __shared__ uint2 res[RROWS][NCAND];
    const int tid = threadIdx.x;
    const int n0 = blockIdx.x * RROWS;
    const int b = n0 >> 10;
    const int hw0 = n0 & 1023;
    const float* xbase = X + (size_t)b * CHW + hw0;
    #pragma unroll
    for (int it = 0; it < RROWS; ++it) {
        int idx = tid + it * 256;
        int d = idx >> 5, r = idx & 31;
        Xl[r][d] = xbase[(size_t)d * HW + r];
    }
    __syncthreads();
    const int r = tid >> 3, c = tid & 7;
    const int n = n0 + r;
    float A;
    {
#pragma clang fp contract(off)
        float r0[8], r1[8];
        #pragma unroll
        for (int j = 0; j < 8; ++j) { float t = Xl[r][j];       r0[j] = t * t; }
        #pragma unroll
        for (int j = 0; j < 8; ++j) { float t = Xl[r][128 + j]; r1[j] = t * t; }
        for (int i = 8; i < 128; i += 8) {
            #pragma unroll
            for (int j = 0; j < 8; ++j) { float t = Xl[r][i + j];       r0[j] += t * t; }
            #pragma unroll
            for (int j = 0; j < 8; ++j) { float t = Xl[r][128 + i + j]; r1[j] += t * t; }
        }
        float lo = ((r0[0]+r0[1])+(r0[2]+r0[3]))+((r0[4]+r0[5])+(r0[6]+r0[7]));
        float hi = ((r1[0]+r1[1])+(r1[2]+r1[3]))+((r1[4]+r1[5])+(r1[6]+r1[7]));
        A = lo + hi;
    }
    int k = ck[(size_t)n * NCAND + c];
    const float4* e4 = reinterpret_cast<const float4*>(E + (size_t)k * DD);
    const float4* x4 = reinterpret_cast<const float4*>(&Xl[r][0]);
    double m0 = 0.0, m1 = 0.0, m2 = 0.0, m3 = 0.0;   // f64 dot: order-free
    for (int i = 0; i < 64; i += 4) {
        float4 ev0 = e4[i],     xv0 = x4[i];
        float4 ev1 = e4[i + 1], xv1 = x4[i + 1];
        float4 ev2 = e4[i + 2], xv2 = x4[i + 2];
        float4 ev3 = e4[i + 3], xv3 = x4[i + 3];
        m0 += (double)ev0.x*xv0.x + (double)ev0.y*xv0.y + (double)ev0.z*xv0.z + (double)ev0.w*xv0.w;
        m1 += (double)ev1.x*xv1.x + (double)ev1.y*xv1.y + (double)ev1.z*xv1.z + (double)ev1.w*xv1.w;
        m2 += (double)ev2.x*xv2.x + (double)ev2.y*xv2.y + (double)ev2.z*xv2.z + (double)ev2.w*xv2.w;
        m3 += (double)ev3.x*xv3.x + (double)ev3.y*xv3.y + (double)ev3.z*xv3.z + (double)ev3.w*xv3.w;
    }
    double m = (m0 + m1) + (m2 + m3);
    float dist;
    {
#pragma clang fp contract(off)
        float M  = (float)m;
        float Bt = 2.0f * M;
        float T1 = A - Bt;
        dist = T1 + Cref[k];
    }
    uint2 pr; pr.x = __float_as_uint(dist); pr.y = (unsigned)k;  // dist > 0 always
    res[r][c] = pr;
    __syncthreads();
    if (tid < RROWS) {
        unsigned bd = 0xFFFFFFFFu; int bk = 0x7FFFFFFF;
        #pragma unroll
        for (int j = 0; j < NCAND; ++j) {
            uint2 p2 = res[tid][j];
            unsigned db = p2.x; int kk = (int)p2.y;
            if (db < bd || (db == bd && kk < bk)) { bd = db; bk = kk; }
        }
        ind[n0 + tid] = bk;
        idx_out_f[n0 + tid] = (float)bk;
    }
}

// ---- out = x + BETA*(E[ind] - x), NCHW, float4 over w ----
__global__ __launch_bounds__(256) void k_out(const float* __restrict__ X,
                                             const float* __restrict__ E,
                                             const int* __restrict__ ind,
                                             float* __restrict__ out) {
    int gid = blockIdx.x * 256 + threadIdx.x;
    int e0 = gid << 2;
    int hw = e0 & 1023;
    int d  = (e0 >> 10) & 255;
    int b  = e0 >> 18;
    int n0 = (b << 10) | hw;

    float4 x = *reinterpret_cast<const float4*>(X + e0);
    int4  iv = *reinterpret_cast<const int4*>(ind + n0);
    float q0 = E[(size_t)iv.x * DD + d];
    float q1 = E[(size_t)iv.y * DD + d];
    float q2 = E[(size_t)iv.z * DD + d];
    float q3 = E[(size_t)iv.w * DD + d];
    float4 r;
    r.x = x.x + BETA * (q0 - x.x);
    r.y = x.y + BETA * (q1 - x.y);
    r.z = x.z + BETA * (q2 - x.z);
    r.w = x.w + BETA * (q3 - x.w);
    *reinterpret_cast<float4*>(out + e0) = r;
}

extern "C" void kernel_launch(void* const* d_in, const int* in_sizes, int n_in,
                              void* d_out, int out_size, void* d_ws, size_t ws_size,
                              hipStream_t stream) {
    const float* lat = (const float*)d_in[0];      // (32,256,32,32) fp32
    const float* emb = (const float*)d_in[1];      // (2048,256) fp32
    float* out   = (float*)d_out;                  // 8388608 floats (output 0)
    float* idx_f = out + (size_t)BB * DD * HW;     // 32768 floats (output 1)

    // Large scratch in d_out's output-0 region (fully overwritten by k_out at
    // the end; all readers precede k_out). d_ws holds 144 KB.
    char*  ob   = (char*)d_out;
    uint4* EbfT = (uint4*)(ob);                    // 1 MB
    int*   ck   = (int*)(ob + 1048576);            // 1 MB (ends at 2 MB < 32 MB)

    char* ws = (char*)d_ws;
    float* Ckey = (float*)(ws + 0);                // 8 KB
    float* Cref = (float*)(ws + 8192);             // 8 KB
    int*   ind  = (int*)(ws + 16384);              // 128 KB

    k_prep   <<<264, 256, 0, stream>>>(emb, EbfT, Cref, Ckey);
    k_screen <<<NN / 128, 512, 0, stream>>>(lat, EbfT, Ckey, ck);
    k_refine <<<NN / RROWS, 256, 0, stream>>>(lat, emb, Cref, ck, idx_f, ind);
    k_out    <<<(BB * DD * HW) / 4 / 256, 256, 0, stream>>>(lat, emb, ind, out);
}

// Round 8
// 189.376 us; speedup vs baseline: 1.1111x; 1.1111x over previous
//
#include <hip/hip_runtime.h>
#include <math.h>

#define BB 32
#define DD 256
#define KK 2048
#define HW 1024
#define CHW (DD*HW)
#define NN (BB*HW)         // 32768 rows
#define BETA 0.25f
#define NCAND 8
#define RROWS 32
#define BIAS 0.125f

typedef __attribute__((ext_vector_type(8))) short short8v;   // 8 bf16 (4 VGPR)
typedef __attribute__((ext_vector_type(4))) float f32x4;

typedef const __attribute__((address_space(1))) void gv_t;
typedef __attribute__((address_space(3))) void lv_t;

__device__ __forceinline__ void gl_lds16(const void* g, void* l) {
    // LDS dest = wave-uniform base (+ lane*16 by HW); global src = per-lane addr
    __builtin_amdgcn_global_load_lds((gv_t*)g, (lv_t*)l, 16, 0, 0);
}

__device__ __forceinline__ unsigned bfr(float f) {           // fp32 -> bf16 RNE
    unsigned u = __float_as_uint(f);
    return (u + 0x7FFFu + ((u >> 16) & 1u)) >> 16;
}
__device__ __forceinline__ unsigned bfpack(float lo, float hi) {
    return bfr(lo) | (bfr(hi) << 16);
}

#define BARRIER() do { asm volatile("" ::: "memory"); \
                       __builtin_amdgcn_s_barrier();  \
                       asm volatile("" ::: "memory"); } while (0)

// ---- prep: blocks 0..255 convert E->bf16 tiled; blocks 256..263 compute C ----
// EbfT unit u = t*2048 + c*256 + kc*64 + code64   (t = 64-code tile)
__global__ __launch_bounds__(256) void k_prep(const float* __restrict__ E,
                                              uint4* __restrict__ EbfT,
                                              float* __restrict__ Cref,
                                              float* __restrict__ Ckey) {
    int bid = blockIdx.x;
    if (bid < 256) {
        int u = bid * 256 + threadIdx.x;                 // 0..65535
        int code = u & 63, kc = (u >> 6) & 3, c = (u >> 8) & 7, t = u >> 11;
        int k = t * 64 + code;
        const float* s = E + ((size_t)k * DD + c * 32 + kc * 8);
        float4 f0 = *reinterpret_cast<const float4*>(s);
        float4 f1 = *reinterpret_cast<const float4*>(s + 4);
        uint4 o;
        o.x = bfpack(f0.x, f0.y); o.y = bfpack(f0.z, f0.w);
        o.z = bfpack(f1.x, f1.y); o.w = bfpack(f1.z, f1.w);
        EbfT[u] = o;
    } else {
        int k = (bid - 256) * 256 + threadIdx.x;
        const float* e = E + (size_t)k * DD;
        float res;
        {
#pragma clang fp contract(off)
            float r0[8], r1[8];
            #pragma unroll
            for (int j = 0; j < 8; ++j) { float t = e[j];       r0[j] = t * t; }
            #pragma unroll
            for (int j = 0; j < 8; ++j) { float t = e[128 + j]; r1[j] = t * t; }
            for (int i = 8; i < 128; i += 8) {
                #pragma unroll
                for (int j = 0; j < 8; ++j) { float t = e[i + j];       r0[j] += t * t; }
                #pragma unroll
                for (int j = 0; j < 8; ++j) { float t = e[128 + i + j]; r1[j] += t * t; }
            }
            float lo = ((r0[0]+r0[1])+(r0[2]+r0[3]))+((r0[4]+r0[5])+(r0[6]+r0[7]));
            float hi = ((r1[0]+r1[1])+(r1[2]+r1[3]))+((r1[4]+r1[5])+(r1[6]+r1[7]));
            res = lo + hi;
        }
        Cref[k] = res;
        Ckey[k] = res + BIAS;
    }
}

// ---- MFMA screen v4: 256 thr (4 waves: 2 row-grp x 2 code-grp), 64 rows/block,
//      grid 512 (2 blocks/CU), A in regs, E dbuf + counted vmcnt ----
__global__ __launch_bounds__(256, 2) void k_screen(
        const float* __restrict__ X, const uint4* __restrict__ EbfT,
        const float* __restrict__ Ckey, uint4* __restrict__ ck)
{
    __shared__ __align__(1024) char lds[73728]; // 2x32KB E dbuf | 8KB ckey

    const int tid = threadIdx.x;
    const int w = tid >> 6;              // 0..3
    const int wr = w >> 1, wc = w & 1;   // 2 row-groups x 2 code-groups
    const int lane = tid & 63;
    const int lid = lane & 15, kc = lane >> 4;
    const int nb = blockIdx.x * 64;
    const int b = nb >> 10;              // 64 | 1024 -> single b per block
    const int hw0 = nb & 1023;

    // Ckey -> LDS (in-loop reads must be LGKM so vmcnt counting stays exact)
    float* ckl = (float*)(lds + 65536);
    #pragma unroll
    for (int i = 0; i < 8; ++i) ckl[tid + i * 256] = Ckey[tid + i * 256];

    // ---- A-fragments: rows hw0+wr*32+rt*16+lid, d = c*32+kc*8+j (64 VGPR) ----
    short8v a[8][2];
    {
        const float* xb = X + (size_t)b * CHW + (hw0 + wr * 32 + lid);
        #pragma unroll
        for (int c = 0; c < 8; ++c)
            #pragma unroll
            for (int rt = 0; rt < 2; ++rt) {
                const float* pp = xb + rt * 16 + (size_t)(c * 32 + kc * 8) * HW;
                float f[8];
                #pragma unroll
                for (int j = 0; j < 8; ++j) f[j] = pp[(size_t)j * HW];
                uint4 v;
                v.x = bfpack(f[0], f[1]); v.y = bfpack(f[2], f[3]);
                v.z = bfpack(f[4], f[5]); v.w = bfpack(f[6], f[7]);
                a[c][rt] = *reinterpret_cast<short8v*>(&v);
            }
    }

    // ---- staging: 4 waves x 8 insts x 1KB = 32KB tile ----
    auto stage = [&](int t, int p) {
        const uint4* src = EbfT + ((size_t)t * 2048 + w * 512 + lane);
        char* dst = lds + p * 32768 + (w * 512) * 16;
        #pragma unroll
        for (int i = 0; i < 8; ++i)
            gl_lds16(src + i * 64, dst + i * 1024);
    };

    stage(0, 0);
    stage(1, 1);
    asm volatile("s_waitcnt lgkmcnt(0)" ::: "memory");   // ckl writes visible
    asm volatile("s_waitcnt vmcnt(8)" ::: "memory");     // tile0 arrived
    BARRIER();

    unsigned t1[2][2][4], t2[2][2][4];                   // top-2 per (rt,ct,g)
    #pragma unroll
    for (int i = 0; i < 2; ++i)
        #pragma unroll
        for (int j = 0; j < 2; ++j)
            #pragma unroll
            for (int g = 0; g < 4; ++g) {
                t1[i][j][g] = 0xFFFFFFFFu; t2[i][j][g] = 0xFFFFFFFFu;
            }

    int p = 0;
    for (int t = 0; t < 32; ++t) {
        const short8v* Ev = reinterpret_cast<const short8v*>(lds + p * 32768);
        float ckv[2];
        #pragma unroll
        for (int ct = 0; ct < 2; ++ct)
            ckv[ct] = ckl[t * 64 + wc * 32 + ct * 16 + lid];

        f32x4 acc[2][2];
        #pragma unroll
        for (int i = 0; i < 2; ++i)
            #pragma unroll
            for (int j = 0; j < 2; ++j) acc[i][j] = (f32x4){0.f, 0.f, 0.f, 0.f};

        #pragma unroll
        for (int c = 0; c < 8; ++c) {
            short8v b0 = Ev[c * 256 + kc * 64 + wc * 32 + lid];
            short8v b1 = Ev[c * 256 + kc * 64 + wc * 32 + 16 + lid];
            acc[0][0] = __builtin_amdgcn_mfma_f32_16x16x32_bf16(a[c][0], b0, acc[0][0], 0, 0, 0);
            acc[1][0] = __builtin_amdgcn_mfma_f32_16x16x32_bf16(a[c][1], b0, acc[1][0], 0, 0, 0);
            acc[0][1] = __builtin_amdgcn_mfma_f32_16x16x32_bf16(a[c][0], b1, acc[0][1], 0, 0, 0);
            acc[1][1] = __builtin_amdgcn_mfma_f32_16x16x32_bf16(a[c][1], b1, acc[1][1], 0, 0, 0);
        }

        // key = (score bits & ~31) | t ; top-2 insert (6 VALU/score)
        #pragma unroll
        for (int rt = 0; rt < 2; ++rt)
            #pragma unroll
            for (int ct = 0; ct < 2; ++ct)
                #pragma unroll
                for (int g = 0; g < 4; ++g) {
                    float s = fmaf(-2.0f, acc[rt][ct][g], ckv[ct]);
                    unsigned key = (__float_as_uint(s) & 0xFFFFFFE0u) | (unsigned)t;
                    unsigned o1 = t1[rt][ct][g];
                    unsigned hi = key > o1 ? key : o1;
                    t1[rt][ct][g] = key < o1 ? key : o1;
                    t2[rt][ct][g] = hi < t2[rt][ct][g] ? hi : t2[rt][ct][g];
                }

        BARRIER();                                   // all done reading buf p
        if (t < 30) {
            stage(t + 2, p);                         // refill buf p
            asm volatile("s_waitcnt vmcnt(8)" ::: "memory");  // t+1 arrived
        } else {
            asm volatile("s_waitcnt vmcnt(0)" ::: "memory");  // final drain
        }
        BARRIER();                                   // next tile fully valid
        p ^= 1;
    }

    // ---- merge: 64 slots/row x 2 keys -> top-8 ----
    uint2* mb = reinterpret_cast<uint2*>(lds);            // [64 rows][64 slots] 32KB
    uint2* scr = reinterpret_cast<uint2*>(lds + 32768);   // [64][4][8] 16KB
    #pragma unroll
    for (int rt = 0; rt < 2; ++rt)
        #pragma unroll
        for (int ct = 0; ct < 2; ++ct)
            #pragma unroll
            for (int g = 0; g < 4; ++g) {
                int row = wr * 32 + rt * 16 + kc * 4 + g;
                int slot = wc * 32 + ct * 16 + lid;
                uint2 v; v.x = t1[rt][ct][g]; v.y = t2[rt][ct][g];
                mb[row * 64 + slot] = v;
            }
    BARRIER();
    {
        int row = tid >> 2, q = tid & 3;
        uint2 kv[16]; int sl[16];
        #pragma unroll
        for (int s = 0; s < 16; ++s) {
            int slot = q * 16 + ((s + tid) & 15);         // bank-spread rotation
            kv[s] = mb[row * 64 + slot];
            sl[s] = slot;
        }
        unsigned prev = 0; int prevj = -1;
        for (int i = 0; i < 8; ++i) {
            unsigned cur = 0xFFFFFFFFu; int curj = 0x7FFFFFFF;
            #pragma unroll
            for (int s = 0; s < 16; ++s) {
                int j0 = sl[s] * 2;
                { unsigned k2=kv[s].x; int j=j0;   if ((k2>prev||(k2==prev&&j>prevj)) && (k2<cur||(k2==cur&&j<curj))) {cur=k2;curj=j;} }
                { unsigned k2=kv[s].y; int j=j0+1; if ((k2>prev||(k2==prev&&j>prevj)) && (k2<cur||(k2==cur&&j<curj))) {cur=k2;curj=j;} }
            }
            uint2 pr; pr.x = cur; pr.y = (unsigned)curj;
            scr[(row * 4 + q) * 8 + i] = pr;
            prev = cur; prevj = curj;
        }
    }
    BARRIER();
    if (tid < 64) {
        unsigned prev = 0; int prevj = -1;
        unsigned short codes[NCAND];
        for (int i = 0; i < NCAND; ++i) {
            unsigned cur = 0xFFFFFFFFu; int curj = 0x7FFFFFFF;
            for (int m = 0; m < 32; ++m) {
                int mm = (m + tid) & 31;
                uint2 pr = scr[tid * 32 + mm];
                unsigned k2 = pr.x; int j = (int)pr.y;
                if ((k2>prev||(k2==prev&&j>prevj)) && (k2<cur||(k2==cur&&j<curj))) {cur=k2;curj=j;}
            }
            prev = cur; prevj = curj;
            codes[i] = (unsigned short)((cur & 31u) * 64 + (curj >> 1));  // t*64+slot
        }
        ck[nb + tid] = *reinterpret_cast<uint4*>(codes);
    }
}

// ---- refine+out: np-fp32 rescore of 8 cands, then fused output write ----
__global__ __launch_bounds__(256) void k_refineout(const float* __restrict__ X,
                                                   const float* __restrict__ E,
                                                   const float* __restrict__ Cref,
                                                   const uint4* __restrict__ ck,
                                                   float* __restrict__ idx_out_f,
                                                   float* __restrict__ out) {
    __shared__ float Xl[RROWS][DD + 4];
    __shared__ uint2 res[RROWS][NCAND];
    __shared__ int bk_l[RROWS];
    const int tid = threadIdx.x;
    const int n0 = blockIdx.x * RROWS;
    const int b = n0 >> 10;
    const int hw0 = n0 & 1023;
    const float* xbase = X + (size_t)b * CHW + hw0;
    #pragma unroll
    for (int it = 0; it < RROWS; ++it) {
        int idx = tid + it * 256;
        int d = idx >> 5, r = idx & 31;
        Xl[r][d] = xbase[(size_t)d * HW + r];
    }
    __syncthreads();
    const int r = tid >> 3, c = tid & 7;
    const int n = n0 + r;
    float A;
    {
#pragma clang fp contract(off)
        float r0[8], r1[8];
        #pragma unroll
        for (int j = 0; j < 8; ++j) { float t = Xl[r][j];       r0[j] = t * t; }
        #pragma unroll
        for (int j = 0; j < 8; ++j) { float t = Xl[r][128 + j]; r1[j] = t * t; }
        for (int i = 8; i < 128; i += 8) {
            #pragma unroll
            for (int j = 0; j < 8; ++j) { float t = Xl[r][i + j];       r0[j] += t * t; }
            #pragma unroll
            for (int j = 0; j < 8; ++j) { float t = Xl[r][128 + i + j]; r1[j] += t * t; }
        }
        float lo = ((r0[0]+r0[1])+(r0[2]+r0[3]))+((r0[4]+r0[5])+(r0[6]+r0[7]));
        float hi = ((r1[0]+r1[1])+(r1[2]+r1[3]))+((r1[4]+r1[5])+(r1[6]+r1[7]));
        A = lo + hi;
    }
    int k;
    {
        uint4 cw = ck[n];
        const unsigned short* cs = reinterpret_cast<const unsigned short*>(&cw);
        k = cs[c];
    }
    const float4* e4 = reinterpret_cast<const float4*>(E + (size_t)k * DD);
    const float4* x4 = reinterpret_cast<const float4*>(&Xl[r][0]);
    double m0 = 0.0, m1 = 0.0, m2 = 0.0, m3 = 0.0;   // f64 dot: order-free
    for (int i = 0; i < 64; i += 4) {
        float4 ev0 = e4[i],     xv0 = x4[i];
        float4 ev1 = e4[i + 1], xv1 = x4[i + 1];
        float4 ev2 = e4[i + 2], xv2 = x4[i + 2];
        float4 ev3 = e4[i + 3], xv3 = x4[i + 3];
        m0 += (double)ev0.x*xv0.x + (double)ev0.y*xv0.y + (double)ev0.z*xv0.z + (double)ev0.w*xv0.w;
        m1 += (double)ev1.x*xv1.x + (double)ev1.y*xv1.y + (double)ev1.z*xv1.z + (double)ev1.w*xv1.w;
        m2 += (double)ev2.x*xv2.x + (double)ev2.y*xv2.y + (double)ev2.z*xv2.z + (double)ev2.w*xv2.w;
        m3 += (double)ev3.x*xv3.x + (double)ev3.y*xv3.y + (double)ev3.z*xv3.z + (double)ev3.w*xv3.w;
    }
    double m = (m0 + m1) + (m2 + m3);
    float dist;
    {
#pragma clang fp contract(off)
        float M  = (float)m;
        float Bt = 2.0f * M;
        float T1 = A - Bt;
        dist = T1 + Cref[k];
    }
    uint2 pr; pr.x = __float_as_uint(dist); pr.y = (unsigned)k;  // dist > 0 always
    res[r][c] = pr;
    __syncthreads();
    if (tid < RROWS) {
        unsigned bd = 0xFFFFFFFFu; int bk = 0x7FFFFFFF;
        #pragma unroll
        for (int j = 0; j < NCAND; ++j) {
            uint2 p2 = res[tid][j];
            unsigned db = p2.x; int kk = (int)p2.y;
            if (db < bd || (db == bd && kk < bk)) { bd = db; bk = kk; }
        }
        bk_l[tid] = bk;
        idx_out_f[n0 + tid] = (float)bk;
    }
    __syncthreads();
    // ---- fused output: out[b][d][hw0+r] = x + BETA*(E[bk[r]][d] - x) ----
    {
        const int rr = tid & 31;               // constant per thread
        const int d0 = tid >> 5;               // 0..7
        const int myk = bk_l[rr];
        const float* erow = E + (size_t)myk * DD;
        float* ob = out + (size_t)b * CHW + hw0 + rr;
        #pragma unroll
        for (int it = 0; it < 32; ++it) {
            int d = d0 + it * 8;
            float x = Xl[rr][d];
            float q = erow[d];
            ob[(size_t)d * HW] = x + BETA * (q - x);
        }
    }
}

extern "C" void kernel_launch(void* const* d_in, const int* in_sizes, int n_in,
                              void* d_out, int out_size, void* d_ws, size_t ws_size,
                              hipStream_t stream) {
    const float* lat = (const float*)d_in[0];      // (32,256,32,32) fp32
    const float* emb = (const float*)d_in[1];      // (2048,256) fp32
    float* out   = (float*)d_out;                  // 8388608 floats (output 0)
    float* idx_f = out + (size_t)BB * DD * HW;     // 32768 floats (output 1)

    // EbfT scratch in d_out (read only by k_screen, which completes before
    // k_refineout writes out). ck/Cref/Ckey in d_ws (~540 KB, under the
    // 656 KB budget proven in round 3).
    char*  ob   = (char*)d_out;
    uint4* EbfT = (uint4*)(ob);                    // 1 MB

    char* ws = (char*)d_ws;
    float* Ckey = (float*)(ws + 0);                // 8 KB
    float* Cref = (float*)(ws + 8192);             // 8 KB
    uint4* ck   = (uint4*)(ws + 16384);            // 512 KB (ushort8 per row)

    k_prep      <<<264, 256, 0, stream>>>(emb, EbfT, Cref, Ckey);
    k_screen    <<<NN / 64, 256, 0, stream>>>(lat, EbfT, Ckey, ck);
    k_refineout <<<NN / RROWS, 256, 0, stream>>>(lat, emb, Cref, ck, idx_f, out);
}

// Round 9
// 186.843 us; speedup vs baseline: 1.1262x; 1.0136x over previous
//
#include <hip/hip_runtime.h>
#include <math.h>

#define BB 32
#define DD 256
#define KK 2048
#define HW 1024
#define CHW (DD*HW)
#define NN (BB*HW)         // 32768 rows
#define BETA 0.25f
#define NCAND 8
#define RROWS 32
#define BIAS 0.125f

typedef __attribute__((ext_vector_type(8))) short short8v;   // 8 bf16 (4 VGPR)
typedef __attribute__((ext_vector_type(4))) float f32x4;

__device__ __forceinline__ unsigned bfr(float f) {           // fp32 -> bf16 RNE
    unsigned u = __float_as_uint(f);
    return (u + 0x7FFFu + ((u >> 16) & 1u)) >> 16;
}
__device__ __forceinline__ unsigned bfpack(float lo, float hi) {
    return bfr(lo) | (bfr(hi) << 16);
}

// ---- prep: blocks 0..255 convert E->bf16 tiled; blocks 256..263 compute C ----
// EbfT unit u = t*2048 + c*256 + kc*64 + code64   (t = 64-code tile)
__global__ __launch_bounds__(256) void k_prep(const float* __restrict__ E,
                                              uint4* __restrict__ EbfT,
                                              float* __restrict__ Cref,
                                              float* __restrict__ Ckey) {
    int bid = blockIdx.x;
    if (bid < 256) {
        int u = bid * 256 + threadIdx.x;                 // 0..65535
        int code = u & 63, kc = (u >> 6) & 3, c = (u >> 8) & 7, t = u >> 11;
        int k = t * 64 + code;
        const float* s = E + ((size_t)k * DD + c * 32 + kc * 8);
        float4 f0 = *reinterpret_cast<const float4*>(s);
        float4 f1 = *reinterpret_cast<const float4*>(s + 4);
        uint4 o;
        o.x = bfpack(f0.x, f0.y); o.y = bfpack(f0.z, f0.w);
        o.z = bfpack(f1.x, f1.y); o.w = bfpack(f1.z, f1.w);
        EbfT[u] = o;
    } else {
        int k = (bid - 256) * 256 + threadIdx.x;
        const float* e = E + (size_t)k * DD;
        float res;
        {
#pragma clang fp contract(off)
            float r0[8], r1[8];
            #pragma unroll
            for (int j = 0; j < 8; ++j) { float t = e[j];       r0[j] = t * t; }
            #pragma unroll
            for (int j = 0; j < 8; ++j) { float t = e[128 + j]; r1[j] = t * t; }
            for (int i = 8; i < 128; i += 8) {
                #pragma unroll
                for (int j = 0; j < 8; ++j) { float t = e[i + j];       r0[j] += t * t; }
                #pragma unroll
                for (int j = 0; j < 8; ++j) { float t = e[128 + i + j]; r1[j] += t * t; }
            }
            float lo = ((r0[0]+r0[1])+(r0[2]+r0[3]))+((r0[4]+r0[5])+(r0[6]+r0[7]));
            float hi = ((r1[0]+r1[1])+(r1[2]+r1[3]))+((r1[4]+r1[5])+(r1[6]+r1[7]));
            res = lo + hi;
        }
        Cref[k] = res;
        Ckey[k] = res + BIAS;
    }
}

// ---- MFMA screen v5: barrier-free. A in regs, B direct global->reg (E is
//      L2-resident: 1MB < 4MB/XCD). 256 thr = 2 row-grp x 2 code-grp waves,
//      64 rows/block, grid 512 (2 blocks/CU). LDS only for the final merge. ----
__global__ __launch_bounds__(256, 2) void k_screen(
        const float* __restrict__ X, const uint4* __restrict__ EbfT,
        const float* __restrict__ Ckey, uint4* __restrict__ ck)
{
    __shared__ __align__(1024) char lds[49152];   // 32KB mb + 16KB scr (merge only)

    const int tid = threadIdx.x;
    const int w = tid >> 6;              // 0..3
    const int wr = w >> 1, wc = w & 1;   // 2 row-groups x 2 code-groups
    const int lane = tid & 63;
    const int lid = lane & 15, kc = lane >> 4;
    const int nb = blockIdx.x * 64;
    const int b = nb >> 10;              // 64 | 1024 -> single b per block
    const int hw0 = nb & 1023;

    // ---- A-fragments: rows hw0+wr*32+rt*16+lid, d = c*32+kc*8+j (64 VGPR) ----
    short8v a[8][2];
    {
        const float* xb = X + (size_t)b * CHW + (hw0 + wr * 32 + lid);
        #pragma unroll
        for (int c = 0; c < 8; ++c)
            #pragma unroll
            for (int rt = 0; rt < 2; ++rt) {
                const float* pp = xb + rt * 16 + (size_t)(c * 32 + kc * 8) * HW;
                float f[8];
                #pragma unroll
                for (int j = 0; j < 8; ++j) f[j] = pp[(size_t)j * HW];
                uint4 v;
                v.x = bfpack(f[0], f[1]); v.y = bfpack(f[2], f[3]);
                v.z = bfpack(f[4], f[5]); v.w = bfpack(f[6], f[7]);
                a[c][rt] = *reinterpret_cast<short8v*>(&v);
            }
    }

    unsigned t1[2][2][4], t2[2][2][4];                   // top-2 per (rt,ct,g)
    #pragma unroll
    for (int i = 0; i < 2; ++i)
        #pragma unroll
        for (int j = 0; j < 2; ++j)
            #pragma unroll
            for (int g = 0; g < 4; ++g) {
                t1[i][j][g] = 0xFFFFFFFFu; t2[i][j][g] = 0xFFFFFFFFu;
            }

    f32x4 acc[2][2];
    #pragma unroll
    for (int i = 0; i < 2; ++i)
        #pragma unroll
        for (int j = 0; j < 2; ++j) acc[i][j] = (f32x4){0.f, 0.f, 0.f, 0.f};

    // per-lane B base: + t*2048 + c*256 + ct*16
    const uint4* ebase = EbfT + (kc * 64 + wc * 32 + lid);
    const float* ckbase = Ckey + (wc * 32 + lid);
    float pckv0 = 0.f, pckv1 = 0.f;

    #pragma unroll 1
    for (int t = 0; t < 32; ++t) {
        // 1) issue tile-t B loads (global->VGPR, L2-hot, coalesced 256B runs)
        uint4 braw[2][8];
        #pragma unroll
        for (int c = 0; c < 8; ++c) {
            braw[0][c] = ebase[t * 2048 + c * 256];
            braw[1][c] = ebase[t * 2048 + c * 256 + 16];
        }
        float nckv0 = ckbase[t * 64];
        float nckv1 = ckbase[t * 64 + 16];

        // 2) selection for tile t-1 (pure VALU — runs while loads are in flight)
        if (t > 0) {
            unsigned tt = (unsigned)(t - 1);
            #pragma unroll
            for (int rt = 0; rt < 2; ++rt)
                #pragma unroll
                for (int ct = 0; ct < 2; ++ct) {
                    float cv = ct ? pckv1 : pckv0;
                    #pragma unroll
                    for (int g = 0; g < 4; ++g) {
                        float s = fmaf(-2.0f, acc[rt][ct][g], cv);
                        unsigned key = (__float_as_uint(s) & 0xFFFFFFE0u) | tt;
                        unsigned o1 = t1[rt][ct][g];
                        unsigned hi = key > o1 ? key : o1;
                        t1[rt][ct][g] = key < o1 ? key : o1;
                        t2[rt][ct][g] = hi < t2[rt][ct][g] ? hi : t2[rt][ct][g];
                        acc[rt][ct][g] = 0.0f;
                    }
                }
        }
        pckv0 = nckv0; pckv1 = nckv1;

        // 3) MFMAs (wait per-operand as loads arrive)
        #pragma unroll
        for (int c = 0; c < 8; ++c) {
            short8v b0 = *reinterpret_cast<short8v*>(&braw[0][c]);
            short8v b1 = *reinterpret_cast<short8v*>(&braw[1][c]);
            acc[0][0] = __builtin_amdgcn_mfma_f32_16x16x32_bf16(a[c][0], b0, acc[0][0], 0, 0, 0);
            acc[1][0] = __builtin_amdgcn_mfma_f32_16x16x32_bf16(a[c][1], b0, acc[1][0], 0, 0, 0);
            acc[0][1] = __builtin_amdgcn_mfma_f32_16x16x32_bf16(a[c][0], b1, acc[0][1], 0, 0, 0);
            acc[1][1] = __builtin_amdgcn_mfma_f32_16x16x32_bf16(a[c][1], b1, acc[1][1], 0, 0, 0);
        }
    }
    // final selection (tile 31)
    {
        unsigned tt = 31u;
        #pragma unroll
        for (int rt = 0; rt < 2; ++rt)
            #pragma unroll
            for (int ct = 0; ct < 2; ++ct) {
                float cv = ct ? pckv1 : pckv0;
                #pragma unroll
                for (int g = 0; g < 4; ++g) {
                    float s = fmaf(-2.0f, acc[rt][ct][g], cv);
                    unsigned key = (__float_as_uint(s) & 0xFFFFFFE0u) | tt;
                    unsigned o1 = t1[rt][ct][g];
                    unsigned hi = key > o1 ? key : o1;
                    t1[rt][ct][g] = key < o1 ? key : o1;
                    t2[rt][ct][g] = hi < t2[rt][ct][g] ? hi : t2[rt][ct][g];
                }
            }
    }

    // ---- merge: 64 slots/row x 2 keys -> top-8 (r8-verbatim) ----
    uint2* mb = reinterpret_cast<uint2*>(lds);            // [64 rows][64 slots] 32KB
    uint2* scr = reinterpret_cast<uint2*>(lds + 32768);   // [64][4][8] 16KB
    #pragma unroll
    for (int rt = 0; rt < 2; ++rt)
        #pragma unroll
        for (int ct = 0; ct < 2; ++ct)
            #pragma unroll
            for (int g = 0; g < 4; ++g) {
                int row = wr * 32 + rt * 16 + kc * 4 + g;
                int slot = wc * 32 + ct * 16 + lid;
                uint2 v; v.x = t1[rt][ct][g]; v.y = t2[rt][ct][g];
                mb[row * 64 + slot] = v;
            }
    __syncthreads();
    {
        int row = tid >> 2, q = tid & 3;
        uint2 kv[16]; int sl[16];
        #pragma unroll
        for (int s = 0; s < 16; ++s) {
            int slot = q * 16 + ((s + tid) & 15);         // bank-spread rotation
            kv[s] = mb[row * 64 + slot];
            sl[s] = slot;
        }
        unsigned prev = 0; int prevj = -1;
        for (int i = 0; i < 8; ++i) {
            unsigned cur = 0xFFFFFFFFu; int curj = 0x7FFFFFFF;
            #pragma unroll
            for (int s = 0; s < 16; ++s) {
                int j0 = sl[s] * 2;
                { unsigned k2=kv[s].x; int j=j0;   if ((k2>prev||(k2==prev&&j>prevj)) && (k2<cur||(k2==cur&&j<curj))) {cur=k2;curj=j;} }
                { unsigned k2=kv[s].y; int j=j0+1; if ((k2>prev||(k2==prev&&j>prevj)) && (k2<cur||(k2==cur&&j<curj))) {cur=k2;curj=j;} }
            }
            uint2 pr; pr.x = cur; pr.y = (unsigned)curj;
            scr[(row * 4 + q) * 8 + i] = pr;
            prev = cur; prevj = curj;
        }
    }
    __syncthreads();
    if (tid < 64) {
        unsigned prev = 0; int prevj = -1;
        unsigned short codes[NCAND];
        for (int i = 0; i < NCAND; ++i) {
            unsigned cur = 0xFFFFFFFFu; int curj = 0x7FFFFFFF;
            for (int m = 0; m < 32; ++m) {
                int mm = (m + tid) & 31;
                uint2 pr = scr[tid * 32 + mm];
                unsigned k2 = pr.x; int j = (int)pr.y;
                if ((k2>prev||(k2==prev&&j>prevj)) && (k2<cur||(k2==cur&&j<curj))) {cur=k2;curj=j;}
            }
            prev = cur; prevj = curj;
            codes[i] = (unsigned short)((cur & 31u) * 64 + (curj >> 1));  // t*64+slot
        }
        ck[nb + tid] = *reinterpret_cast<uint4*>(codes);
    }
}

// ---- refine+out: np-fp32 rescore of 8 cands, then fused output write ----
__global__ __launch_bounds__(256) void k_refineout(const float* __restrict__ X,
                                                   const float* __restrict__ E,
                                                   const float* __restrict__ Cref,
                                                   const uint4* __restrict__ ck,
                                                   float* __restrict__ idx_out_f,
                                                   float* __restrict__ out) {
    __shared__ float Xl[RROWS][DD + 4];
    __shared__ uint2 res[RROWS][NCAND];
    __shared__ int bk_l[RROWS];
    const int tid = threadIdx.x;
    const int n0 = blockIdx.x * RROWS;
    const int b = n0 >> 10;
    const int hw0 = n0 & 1023;
    const float* xbase = X + (size_t)b * CHW + hw0;
    #pragma unroll
    for (int it = 0; it < RROWS; ++it) {
        int idx = tid + it * 256;
        int d = idx >> 5, r = idx & 31;
        Xl[r][d] = xbase[(size_t)d * HW + r];
    }
    __syncthreads();
    const int r = tid >> 3, c = tid & 7;
    const int n = n0 + r;
    float A;
    {
#pragma clang fp contract(off)
        float r0[8], r1[8];
        #pragma unroll
        for (int j = 0; j < 8; ++j) { float t = Xl[r][j];       r0[j] = t * t; }
        #pragma unroll
        for (int j = 0; j < 8; ++j) { float t = Xl[r][128 + j]; r1[j] = t * t; }
        for (int i = 8; i < 128; i += 8) {
            #pragma unroll
            for (int j = 0; j < 8; ++j) { float t = Xl[r][i + j];       r0[j] += t * t; }
            #pragma unroll
            for (int j = 0; j < 8; ++j) { float t = Xl[r][128 + i + j]; r1[j] += t * t; }
        }
        float lo = ((r0[0]+r0[1])+(r0[2]+r0[3]))+((r0[4]+r0[5])+(r0[6]+r0[7]));
        float hi = ((r1[0]+r1[1])+(r1[2]+r1[3]))+((r1[4]+r1[5])+(r1[6]+r1[7]));
        A = lo + hi;
    }
    int k;
    {
        uint4 cw = ck[n];
        const unsigned short* cs = reinterpret_cast<const unsigned short*>(&cw);
        k = cs[c];
    }
    const float4* e4 = reinterpret_cast<const float4*>(E + (size_t)k * DD);
    const float4* x4 = reinterpret_cast<const float4*>(&Xl[r][0]);
    double m0 = 0.0, m1 = 0.0, m2 = 0.0, m3 = 0.0;   // f64 dot: order-free
    for (int i = 0; i < 64; i += 4) {
        float4 ev0 = e4[i],     xv0 = x4[i];
        float4 ev1 = e4[i + 1], xv1 = x4[i + 1];
        float4 ev2 = e4[i + 2], xv2 = x4[i + 2];
        float4 ev3 = e4[i + 3], xv3 = x4[i + 3];
        m0 += (double)ev0.x*xv0.x + (double)ev0.y*xv0.y + (double)ev0.z*xv0.z + (double)ev0.w*xv0.w;
        m1 += (double)ev1.x*xv1.x + (double)ev1.y*xv1.y + (double)ev1.z*xv1.z + (double)ev1.w*xv1.w;
        m2 += (double)ev2.x*xv2.x + (double)ev2.y*xv2.y + (double)ev2.z*xv2.z + (double)ev2.w*xv2.w;
        m3 += (double)ev3.x*xv3.x + (double)ev3.y*xv3.y + (double)ev3.z*xv3.z + (double)ev3.w*xv3.w;
    }
    double m = (m0 + m1) + (m2 + m3);
    float dist;
    {
#pragma clang fp contract(off)
        float M  = (float)m;
        float Bt = 2.0f * M;
        float T1 = A - Bt;
        dist = T1 + Cref[k];
    }
    uint2 pr; pr.x = __float_as_uint(dist); pr.y = (unsigned)k;  // dist > 0 always
    res[r][c] = pr;
    __syncthreads();
    if (tid < RROWS) {
        unsigned bd = 0xFFFFFFFFu; int bk = 0x7FFFFFFF;
        #pragma unroll
        for (int j = 0; j < NCAND; ++j) {
            uint2 p2 = res[tid][j];
            unsigned db = p2.x; int kk = (int)p2.y;
            if (db < bd || (db == bd && kk < bk)) { bd = db; bk = kk; }
        }
        bk_l[tid] = bk;
        idx_out_f[n0 + tid] = (float)bk;
    }
    __syncthreads();
    // ---- fused output: out[b][d][hw0+r] = x + BETA*(E[bk[r]][d] - x) ----
    {
        const int rr = tid & 31;               // constant per thread
        const int d0 = tid >> 5;               // 0..7
        const int myk = bk_l[rr];
        const float* erow = E + (size_t)myk * DD;
        float* ob = out + (size_t)b * CHW + hw0 + rr;
        #pragma unroll
        for (int it = 0; it < 32; ++it) {
            int d = d0 + it * 8;
            float x = Xl[rr][d];
            float q = erow[d];
            ob[(size_t)d * HW] = x + BETA * (q - x);
        }
    }
}

extern "C" void kernel_launch(void* const* d_in, const int* in_sizes, int n_in,
                              void* d_out, int out_size, void* d_ws, size_t ws_size,
                              hipStream_t stream) {
    const float* lat = (const float*)d_in[0];      // (32,256,32,32) fp32
    const float* emb = (const float*)d_in[1];      // (2048,256) fp32
    float* out   = (float*)d_out;                  // 8388608 floats (output 0)
    float* idx_f = out + (size_t)BB * DD * HW;     // 32768 floats (output 1)

    // EbfT scratch in d_out (read only by k_screen, which completes before
    // k_refineout writes out). ck/Cref/Ckey in d_ws (~540 KB).
    char*  ob   = (char*)d_out;
    uint4* EbfT = (uint4*)(ob);                    // 1 MB

    char* ws = (char*)d_ws;
    float* Ckey = (float*)(ws + 0);                // 8 KB
    float* Cref = (float*)(ws + 8192);             // 8 KB
    uint4* ck   = (uint4*)(ws + 16384);            // 512 KB (ushort8 per row)

    k_prep      <<<264, 256, 0, stream>>>(emb, EbfT, Cref, Ckey);
    k_screen    <<<NN / 64, 256, 0, stream>>>(lat, EbfT, Ckey, ck);
    k_refineout <<<NN / RROWS, 256, 0, stream>>>(lat, emb, Cref, ck, idx_f, out);
}